// Round 4
// baseline (340.636 us; speedup 1.0000x reference)
//
#include <hip/hip_runtime.h>
#include <hip/hip_bf16.h>

typedef __bf16 bf16x8 __attribute__((ext_vector_type(8)));
typedef __bf16 bf16x4 __attribute__((ext_vector_type(4)));
typedef float  f32x4  __attribute__((ext_vector_type(4)));

#define DM 1024
#define PD 3328
#define TROWS 8192   // bs*seq = 2*4096
#define SEQ 4096

__device__ __forceinline__ float sigmoidf(float x) { return 1.f / (1.f + __expf(-x)); }

// ---------------- transpose + f32->bf16 convert:  in[K][N] f32 -> out[N][K] bf16
__global__ __launch_bounds__(256) void tcvt_kernel(const float* __restrict__ in,
                                                   __bf16* __restrict__ out,
                                                   int K, int N) {
  __shared__ float tile[32][33];
  int n0 = blockIdx.x * 32, k0 = blockIdx.y * 32;
  int tx = threadIdx.x, ty = threadIdx.y;     // 32 x 8
  for (int i = ty; i < 32; i += 8) tile[i][tx] = in[(size_t)(k0 + i) * N + n0 + tx];
  __syncthreads();
  for (int i = ty; i < 32; i += 8) out[(size_t)(n0 + i) * K + k0 + tx] = (__bf16)tile[tx][i];
}

// ---------------- RMSNorm -> bf16
__global__ __launch_bounds__(256) void rmsnorm_kernel(const float* __restrict__ hidden,
                                                      const float* __restrict__ w,
                                                      __bf16* __restrict__ hbf) {
  int r = blockIdx.x;
  int tid = threadIdx.x;
  float4 v = ((const float4*)(hidden + (size_t)r * DM))[tid];
  float ss = v.x * v.x + v.y * v.y + v.z * v.z + v.w * v.w;
#pragma unroll
  for (int off = 32; off > 0; off >>= 1) ss += __shfl_xor(ss, off);
  __shared__ float wsum[4];
  int lane = tid & 63, wid = tid >> 6;
  if (lane == 0) wsum[wid] = ss;
  __syncthreads();
  float tot = wsum[0] + wsum[1] + wsum[2] + wsum[3];
  float inv = rsqrtf(tot * (1.f / 1024.f) + 1e-6f);
  float4 wl = ((const float4*)w)[tid];
  bf16x4 o;
  o[0] = (__bf16)(v.x * inv * wl.x);
  o[1] = (__bf16)(v.y * inv * wl.y);
  o[2] = (__bf16)(v.z * inv * wl.z);
  o[3] = (__bf16)(v.w * inv * wl.w);
  *(bf16x4*)(hbf + (size_t)r * DM + tid * 4) = o;
}

// ---------------- register-direct MFMA GEMM: no LDS, no barriers.
// A[M][K] bf16, Bt[N][K] bf16. Wave tile 64(m) x 128(n); block = 2x2 waves
// = 128 x 256. Fragments (16 rows x 64B) loaded straight from global (L2-hot),
// double-buffered across the two 32-wide k-slices of each 64-wide K-step.
template <int K, int EPI>
__global__ __launch_bounds__(256, 2) void gemmreg(
    const __bf16* __restrict__ A, const __bf16* __restrict__ Bt,
    int N_out,
    const float* __restrict__ gate_bias, const float* __restrict__ shortcut,
    float* __restrict__ outf, __bf16* __restrict__ zbf, __bf16* __restrict__ xbf,
    float* __restrict__ gf, __bf16* __restrict__ qbf, __bf16* __restrict__ kbf) {
  const int tid = threadIdx.x;
  const int lane = tid & 63, wid = tid >> 6;
  const int wr = wid >> 1, wc = wid & 1;

  // XCD-aware swizzle (grid sizes are multiples of 8); n-fastest so that
  // consecutive blocks on one XCD share the A panel in its L2.
  const int nwg = gridDim.x;
  const int cpx = nwg >> 3;
  const int swz = (blockIdx.x & 7) * cpx + (blockIdx.x >> 3);
  const int ntx = N_out / 256;
  const int m0 = (swz / ntx) * 128 + wr * 64;
  const int n0 = (swz % ntx) * 256 + wc * 128;

  const int row = lane & 15, hi = lane >> 4;

  // per-lane fragment base pointers (row + k-sub-slot folded in)
  const __bf16* Ab = A + (size_t)(m0 + row) * K + hi * 8;
  const __bf16* Bb = Bt + (size_t)(n0 + row) * K + hi * 8;

#define LDA(m, koff) (*(const bf16x8*)(Ab + (size_t)(m) * 16 * K + (koff)))
#define LDB(n, koff) (*(const bf16x8*)(Bb + (size_t)(n) * 16 * K + (koff)))

  f32x4 acc[4][8] = {};
  bf16x8 a0[4], b0[8], a1[4], b1[8];

  // prologue: slice k=0
#pragma unroll
  for (int m = 0; m < 4; ++m) a0[m] = LDA(m, 0);
#pragma unroll
  for (int n = 0; n < 8; ++n) b0[n] = LDB(n, 0);

  for (int kt = 0; kt < K; kt += 64) {
    const bool more = (kt + 64) < K;
    // load slice kt+32 (always in-range)
#pragma unroll
    for (int m = 0; m < 4; ++m) a1[m] = LDA(m, kt + 32);
#pragma unroll
    for (int n = 0; n < 8; ++n) b1[n] = LDB(n, kt + 32);
    // MFMA slice kt
#pragma unroll
    for (int m = 0; m < 4; ++m)
#pragma unroll
      for (int n = 0; n < 8; ++n)
        acc[m][n] = __builtin_amdgcn_mfma_f32_16x16x32_bf16(a0[m], b0[n], acc[m][n], 0, 0, 0);
    // load slice kt+64 (next K-step) if any
    if (more) {
#pragma unroll
      for (int m = 0; m < 4; ++m) a0[m] = LDA(m, kt + 64);
#pragma unroll
      for (int n = 0; n < 8; ++n) b0[n] = LDB(n, kt + 64);
    }
    // MFMA slice kt+32
#pragma unroll
    for (int m = 0; m < 4; ++m)
#pragma unroll
      for (int n = 0; n < 8; ++n)
        acc[m][n] = __builtin_amdgcn_mfma_f32_16x16x32_bf16(a1[m], b1[n], acc[m][n], 0, 0, 0);
  }
#undef LDA
#undef LDB

  // epilogue: C/D map col=lane&15, row=(lane>>4)*4+i
#pragma unroll
  for (int m = 0; m < 4; ++m) {
#pragma unroll
    for (int n = 0; n < 8; ++n) {
#pragma unroll
      for (int i = 0; i < 4; ++i) {
        int r = m0 + m * 16 + hi * 4 + i;
        int c = n0 + n * 16 + row;
        float v = acc[m][n][i];
        if (EPI == 1) {
          if (c < 1024)       zbf[(size_t)r * DM + c] = (__bf16)sigmoidf(v);
          else if (c < 2048)  xbf[(size_t)r * DM + (c - 1024)] = (__bf16)v;
          else if (c < 3072)  gf[(size_t)r * DM + (c - 2048)] = sigmoidf(v + gate_bias[c - 2048]);
          else if (c < 3200)  qbf[(size_t)r * 128 + (c - 3072)] = (__bf16)v;
          else                kbf[(size_t)r * 128 + (c - 3200)] = (__bf16)v;
        } else {
          outf[(size_t)r * DM + c] = v + shortcut[(size_t)r * DM + c];
        }
      }
    }
  }
}

// ---------------- per-chunk first-order scan (f32 state), thread = one d-channel
__global__ __launch_bounds__(256) void scan_kernel(const float* __restrict__ g,
                                                   const __bf16* __restrict__ x,
                                                   const __bf16* __restrict__ kin,
                                                   __bf16* __restrict__ ixa,
                                                   __bf16* __restrict__ ika) {
  int bx = blockIdx.x;            // 2*64*4 = 512 blocks
  int part = bx & 3;
  int c = (bx >> 2) & 63;
  int b = bx >> 8;
  int d = part * 256 + threadIdx.x;
  size_t base = (size_t)b * SEQ + (size_t)c * 64;
  float sx = 0.f, sk = 0.f;
  for (int t = 0; t < 64; ++t) {
    size_t row = base + t;
    float gg = g[row * DM + d];
    float xv = (float)x[row * DM + d];
    float kv = (float)kin[row * 128 + (d & 127)];
    sx = gg * (sx - xv) + xv;   // = g*prev + (1-g)*x
    sk = gg * (sk - kv) + kv;
    ixa[row * DM + d] = (__bf16)sx;
    ika[row * DM + d] = (__bf16)sk;
  }
}

// ---------------- attention: block = (qtile 64 queries, head, batch); 4 waves
__global__ __launch_bounds__(256) void attn_kernel(const __bf16* __restrict__ qbf,
                                                   const __bf16* __restrict__ ixa,
                                                   const __bf16* __restrict__ ika,
                                                   const __bf16* __restrict__ zbf,
                                                   __bf16* __restrict__ y) {
  const int qt = blockIdx.x;   // 0..63 query chunk
  const int h  = blockIdx.y;   // 0..15
  const int b  = blockIdx.z;   // 0..1
  const int tid = threadIdx.x;
  const int lane = tid & 63, wd = tid >> 6;

  __shared__ __bf16 qs[64 * 72];
  __shared__ __bf16 ck[64 * 72];
  __shared__ __bf16 cxT[64 * 72];
  __shared__ __bf16 pb[64 * 72];
  __shared__ float sc[64 * 65];
  __shared__ float rden[64], iwd[64];

  const size_t base = (size_t)b * SEQ;

  for (int i = tid; i < 512; i += 256) {
    int row = i >> 3, part = i & 7;
    *(bf16x8*)&qs[row * 72 + part * 8] =
        *(const bf16x8*)&qbf[(base + qt * 64 + row) * 128 + (h & 1) * 64 + part * 8];
    *(bf16x8*)&ck[row * 72 + part * 8] =
        *(const bf16x8*)&ika[(base + (size_t)row * 64) * DM + h * 64 + part * 8];
  }
  for (int i = tid; i < 4096; i += 256) {
    int c = i & 63, j = i >> 6;
    cxT[j * 72 + c] = ixa[(base + (size_t)c * 64) * DM + h * 64 + j];
  }
  __syncthreads();

  {
    f32x4 d4[4] = {};
#pragma unroll
    for (int kk = 0; kk < 64; kk += 32) {
      bf16x8 a = *(const bf16x8*)&qs[(wd * 16 + (lane & 15)) * 72 + kk + (lane >> 4) * 8];
#pragma unroll
      for (int ni = 0; ni < 4; ++ni) {
        bf16x8 bb = *(const bf16x8*)&ck[(ni * 16 + (lane & 15)) * 72 + kk + (lane >> 4) * 8];
        d4[ni] = __builtin_amdgcn_mfma_f32_16x16x32_bf16(a, bb, d4[ni], 0, 0, 0);
      }
    }
#pragma unroll
    for (int ni = 0; ni < 4; ++ni)
#pragma unroll
      for (int i = 0; i < 4; ++i) {
        int qrow = wd * 16 + (lane >> 4) * 4 + i;
        int c = ni * 16 + (lane & 15);
        sc[qrow * 65 + c] = 0.125f * d4[ni][i];
      }
  }

  float lse = 0.f;
  if (tid < 64) {
    const __bf16* qrow = &qbf[(base + qt * 64 + tid) * 128 + (h & 1) * 64];
    const __bf16* krow = &ika[(base + qt * 64 + tid) * DM + h * 64];
    float dot = 0.f;
#pragma unroll
    for (int p = 0; p < 8; ++p) {
      bf16x8 qa = *(const bf16x8*)&qrow[p * 8];
      bf16x8 ka = *(const bf16x8*)&krow[p * 8];
#pragma unroll
      for (int e = 0; e < 8; ++e) dot += (float)qa[e] * (float)ka[e];
    }
    lse = 0.125f * dot;
  }
  __syncthreads();

  if (tid < 64) {
    int q = tid;
    float m = lse;
    for (int c = 0; c < qt; ++c) m = fmaxf(m, sc[q * 65 + c]);
    float den = 0.f;
    for (int c = 0; c < 64; ++c) {
      float wv = (c < qt) ? __expf(sc[q * 65 + c] - m) : 0.f;
      pb[q * 72 + c] = (__bf16)wv;
      den += wv;
    }
    float iw = __expf(lse - m);
    den += iw;
    rden[q] = 1.f / den;
    iwd[q] = iw;
  }
  __syncthreads();

  {
    f32x4 d4[4] = {};
#pragma unroll
    for (int kk = 0; kk < 64; kk += 32) {
      bf16x8 a = *(const bf16x8*)&pb[(wd * 16 + (lane & 15)) * 72 + kk + (lane >> 4) * 8];
#pragma unroll
      for (int ni = 0; ni < 4; ++ni) {
        bf16x8 bb = *(const bf16x8*)&cxT[(ni * 16 + (lane & 15)) * 72 + kk + (lane >> 4) * 8];
        d4[ni] = __builtin_amdgcn_mfma_f32_16x16x32_bf16(a, bb, d4[ni], 0, 0, 0);
      }
    }
#pragma unroll
    for (int ni = 0; ni < 4; ++ni)
#pragma unroll
      for (int i = 0; i < 4; ++i) {
        int qrow = wd * 16 + (lane >> 4) * 4 + i;
        int j = ni * 16 + (lane & 15);
        size_t srow = base + qt * 64 + qrow;
        float ix = (float)ixa[srow * DM + h * 64 + j];
        float outv = (d4[ni][i] + iwd[qrow] * ix) * rden[qrow];
        float zv = (float)zbf[srow * DM + h * 64 + j];
        y[srow * DM + h * 64 + j] = (__bf16)(outv * zv);
      }
  }
}

// ---------------- launcher
extern "C" void kernel_launch(void* const* d_in, const int* in_sizes, int n_in,
                              void* d_out, int out_size, void* d_ws, size_t ws_size,
                              hipStream_t stream) {
  const float* hidden = (const float*)d_in[0];
  const float* rmsw   = (const float*)d_in[1];
  const float* Win    = (const float*)d_in[2];
  const float* gbias  = (const float*)d_in[3];
  const float* Wout   = (const float*)d_in[4];
  float* out = (float*)d_out;

  char* ws = (char*)d_ws;
  size_t o = 0;
  auto alloc = [&](size_t bytes) { char* p = ws + o; o += (bytes + 255) & ~(size_t)255; return p; };
  __bf16* WinT  = (__bf16*)alloc((size_t)PD * DM * 2);
  __bf16* WoutT = (__bf16*)alloc((size_t)DM * DM * 2);
  __bf16* hy    = (__bf16*)alloc((size_t)TROWS * DM * 2);  // h_bf, reused as y after GEMM1
  __bf16* zbf   = (__bf16*)alloc((size_t)TROWS * DM * 2);
  __bf16* xbf   = (__bf16*)alloc((size_t)TROWS * DM * 2);
  float*  gf    = (float*)alloc((size_t)TROWS * DM * 4);
  __bf16* qbf   = (__bf16*)alloc((size_t)TROWS * 128 * 2);
  __bf16* kbf   = (__bf16*)alloc((size_t)TROWS * 128 * 2);
  __bf16* ixa   = (__bf16*)alloc((size_t)TROWS * DM * 2);
  __bf16* ika   = (__bf16*)alloc((size_t)TROWS * DM * 2);

  tcvt_kernel<<<dim3(PD / 32, DM / 32), dim3(32, 8), 0, stream>>>(Win, WinT, DM, PD);
  tcvt_kernel<<<dim3(DM / 32, DM / 32), dim3(32, 8), 0, stream>>>(Wout, WoutT, DM, DM);
  rmsnorm_kernel<<<TROWS, 256, 0, stream>>>(hidden, rmsw, hy);
  // GEMM1: M=8192, N=3328 -> (8192/128)*(3328/256) = 64*13 = 832 blocks
  gemmreg<DM, 1><<<dim3(832), 256, 0, stream>>>(
      hy, WinT, PD, gbias, nullptr, nullptr, zbf, xbf, gf, qbf, kbf);
  scan_kernel<<<512, 256, 0, stream>>>(gf, xbf, kbf, ixa, ika);
  attn_kernel<<<dim3(64, 16, 2), 256, 0, stream>>>(qbf, ixa, ika, zbf, hy);
  // GEMM2: M=8192, N=1024 -> 64*4 = 256 blocks
  gemmreg<DM, 0><<<dim3(256), 256, 0, stream>>>(
      hy, WoutT, DM, nullptr, hidden, out, nullptr, nullptr, nullptr, nullptr, nullptr);
}

// Round 5
// 214.807 us; speedup vs baseline: 1.5858x; 1.5858x over previous
//
#include <hip/hip_runtime.h>
#include <hip/hip_bf16.h>

typedef __bf16 bf16x8 __attribute__((ext_vector_type(8)));
typedef __bf16 bf16x4 __attribute__((ext_vector_type(4)));
typedef float  f32x4  __attribute__((ext_vector_type(4)));

#define DM 1024
#define PD 3328
#define TROWS 8192   // bs*seq = 2*4096
#define SEQ 4096

__device__ __forceinline__ float sigmoidf(float x) { return 1.f / (1.f + __expf(-x)); }

__device__ __forceinline__ void gload16(const void* g, void* l) {
  __builtin_amdgcn_global_load_lds(
      (const __attribute__((address_space(1))) void*)g,
      (__attribute__((address_space(3))) void*)l, 16, 0, 0);
}

// ---------------- transpose + f32->bf16 convert:  in[K][N] f32 -> out[N][K] bf16
__global__ __launch_bounds__(256) void tcvt_kernel(const float* __restrict__ in,
                                                   __bf16* __restrict__ out,
                                                   int K, int N) {
  __shared__ float tile[32][33];
  int n0 = blockIdx.x * 32, k0 = blockIdx.y * 32;
  int tx = threadIdx.x, ty = threadIdx.y;     // 32 x 8
  for (int i = ty; i < 32; i += 8) tile[i][tx] = in[(size_t)(k0 + i) * N + n0 + tx];
  __syncthreads();
  for (int i = ty; i < 32; i += 8) out[(size_t)(n0 + i) * K + k0 + tx] = (__bf16)tile[tx][i];
}

// ---------------- RMSNorm -> bf16
__global__ __launch_bounds__(256) void rmsnorm_kernel(const float* __restrict__ hidden,
                                                      const float* __restrict__ w,
                                                      __bf16* __restrict__ hbf) {
  int r = blockIdx.x;
  int tid = threadIdx.x;
  float4 v = ((const float4*)(hidden + (size_t)r * DM))[tid];
  float ss = v.x * v.x + v.y * v.y + v.z * v.z + v.w * v.w;
#pragma unroll
  for (int off = 32; off > 0; off >>= 1) ss += __shfl_xor(ss, off);
  __shared__ float wsum[4];
  int lane = tid & 63, wid = tid >> 6;
  if (lane == 0) wsum[wid] = ss;
  __syncthreads();
  float tot = wsum[0] + wsum[1] + wsum[2] + wsum[3];
  float inv = rsqrtf(tot * (1.f / 1024.f) + 1e-6f);
  float4 wl = ((const float4*)w)[tid];
  bf16x4 o;
  o[0] = (__bf16)(v.x * inv * wl.x);
  o[1] = (__bf16)(v.y * inv * wl.y);
  o[2] = (__bf16)(v.z * inv * wl.z);
  o[3] = (__bf16)(v.w * inv * wl.w);
  *(bf16x4*)(hbf + (size_t)r * DM + tid * 4) = o;
}

// ---------------- T3-minimum 2-phase MFMA GEMM: 128x128 tile, BK=64,
// double-buffered 64 KiB LDS (2 blocks/CU co-resident), ONE barrier per
// K-step. Per step: stage(t+1) -> ds_read frags(t) -> MFMA -> vmcnt(0) ->
// s_barrier. LDS rows are 64 elems (128B) with 16B-slot XOR swizzle
// (slot ^= row&7) -> conflict-free ds_read_b128 (verified R2: conflicts=0).
template <int EPI>
__global__ __launch_bounds__(256, 2) void gemm2p(
    const __bf16* __restrict__ A, const __bf16* __restrict__ Bt,
    int N_out, int K,
    const float* __restrict__ gate_bias, const float* __restrict__ shortcut,
    float* __restrict__ outf, __bf16* __restrict__ zbf, __bf16* __restrict__ xbf,
    float* __restrict__ gf, __bf16* __restrict__ qbf, __bf16* __restrict__ kbf) {
  __shared__ __bf16 As[2][128 * 64];
  __shared__ __bf16 Bs[2][128 * 64];

  const int tid = threadIdx.x;
  const int lane = tid & 63, wid = tid >> 6;
  const int wr = wid >> 1, wc = wid & 1;

  // XCD-aware bijective swizzle (grid sizes are multiples of 8)
  const int nwg = gridDim.x;
  const int cpx = nwg >> 3;
  const int swz = (blockIdx.x & 7) * cpx + (blockIdx.x >> 3);
  const int ntx = N_out >> 7;
  const int m0 = (swz / ntx) << 7;
  const int n0 = (swz % ntx) << 7;

  f32x4 acc[4][4] = {};
  const int NT = K >> 6;

  const int arow0 = wr * 64 + (lane & 15);
  const int brow0 = wc * 64 + (lane & 15);

  auto stage = [&](const __bf16* src, int row0, int kt, __bf16* lbuf) {
#pragma unroll
    for (int j = 0; j < 4; ++j) {
      int off16 = tid + j * 256;        // 16B-chunk index; 8 chunks per row
      int row = off16 >> 3, slot = off16 & 7;
      int col = (slot ^ (row & 7)) << 3;  // inverse swizzle on the SOURCE
      gload16(&src[(size_t)(row0 + row) * K + kt + col], lbuf + off16 * 8);
    }
  };
  auto fragrd = [&](const __bf16* buf, int row, int ks) -> bf16x8 {
    int s = ((ks << 2) + (lane >> 4)) ^ (row & 7);   // swizzled read
    return *(const bf16x8*)&buf[(row << 6) + (s << 3)];
  };

  // prologue: tile 0
  stage(A, m0, 0, &As[0][0]);
  stage(Bt, n0, 0, &Bs[0][0]);
  asm volatile("s_waitcnt vmcnt(0)" ::: "memory");
  __builtin_amdgcn_s_barrier();

  for (int t = 0; t < NT; ++t) {
    const __bf16* Ap = &As[t & 1][0];
    const __bf16* Bp = &Bs[t & 1][0];
    // issue next-tile staging first; it stays in flight under this step's
    // ds_reads + MFMAs (~1400 cyc), then drained by the single vmcnt(0).
    if (t + 1 < NT) {
      stage(A, m0, (t + 1) << 6, &As[(t + 1) & 1][0]);
      stage(Bt, n0, (t + 1) << 6, &Bs[(t + 1) & 1][0]);
    }
#pragma unroll
    for (int ks = 0; ks < 2; ++ks) {
      bf16x8 af[4], bf[4];
#pragma unroll
      for (int m = 0; m < 4; ++m) af[m] = fragrd(Ap, arow0 + m * 16, ks);
#pragma unroll
      for (int n = 0; n < 4; ++n) bf[n] = fragrd(Bp, brow0 + n * 16, ks);
      __builtin_amdgcn_s_setprio(1);
#pragma unroll
      for (int m = 0; m < 4; ++m)
#pragma unroll
        for (int n = 0; n < 4; ++n)
          acc[m][n] = __builtin_amdgcn_mfma_f32_16x16x32_bf16(af[m], bf[n], acc[m][n], 0, 0, 0);
      __builtin_amdgcn_s_setprio(0);
    }
    asm volatile("s_waitcnt vmcnt(0)" ::: "memory");
    __builtin_amdgcn_s_barrier();
  }

  // epilogue: C/D map col=lane&15, row=(lane>>4)*4+i
#pragma unroll
  for (int m = 0; m < 4; ++m) {
#pragma unroll
    for (int n = 0; n < 4; ++n) {
#pragma unroll
      for (int i = 0; i < 4; ++i) {
        int r = m0 + wr * 64 + m * 16 + ((lane >> 4) << 2) + i;
        int c = n0 + wc * 64 + n * 16 + (lane & 15);
        float v = acc[m][n][i];
        if (EPI == 1) {
          if (c < 1024)       zbf[(size_t)r * DM + c] = (__bf16)sigmoidf(v);
          else if (c < 2048)  xbf[(size_t)r * DM + (c - 1024)] = (__bf16)v;
          else if (c < 3072)  gf[(size_t)r * DM + (c - 2048)] = sigmoidf(v + gate_bias[c - 2048]);
          else if (c < 3200)  qbf[(size_t)r * 128 + (c - 3072)] = (__bf16)v;
          else                kbf[(size_t)r * 128 + (c - 3200)] = (__bf16)v;
        } else {
          outf[(size_t)r * DM + c] = v + shortcut[(size_t)r * DM + c];
        }
      }
    }
  }
}

// ---------------- per-chunk first-order scan (f32 state), thread = one d-channel
__global__ __launch_bounds__(256) void scan_kernel(const float* __restrict__ g,
                                                   const __bf16* __restrict__ x,
                                                   const __bf16* __restrict__ kin,
                                                   __bf16* __restrict__ ixa,
                                                   __bf16* __restrict__ ika) {
  int bx = blockIdx.x;            // 2*64*4 = 512 blocks
  int part = bx & 3;
  int c = (bx >> 2) & 63;
  int b = bx >> 8;
  int d = part * 256 + threadIdx.x;
  size_t base = (size_t)b * SEQ + (size_t)c * 64;
  float sx = 0.f, sk = 0.f;
  for (int t = 0; t < 64; ++t) {
    size_t row = base + t;
    float gg = g[row * DM + d];
    float xv = (float)x[row * DM + d];
    float kv = (float)kin[row * 128 + (d & 127)];
    sx = gg * (sx - xv) + xv;   // = g*prev + (1-g)*x
    sk = gg * (sk - kv) + kv;
    ixa[row * DM + d] = (__bf16)sx;
    ika[row * DM + d] = (__bf16)sk;
  }
}

// ---------------- attention: block = (qtile 64 queries, head, batch); 4 waves
__global__ __launch_bounds__(256) void attn_kernel(const __bf16* __restrict__ qbf,
                                                   const __bf16* __restrict__ ixa,
                                                   const __bf16* __restrict__ ika,
                                                   const __bf16* __restrict__ zbf,
                                                   __bf16* __restrict__ y) {
  const int qt = blockIdx.x;   // 0..63 query chunk
  const int h  = blockIdx.y;   // 0..15
  const int b  = blockIdx.z;   // 0..1
  const int tid = threadIdx.x;
  const int lane = tid & 63, wd = tid >> 6;

  __shared__ __bf16 qs[64 * 72];
  __shared__ __bf16 ck[64 * 72];
  __shared__ __bf16 cxT[64 * 72];
  __shared__ __bf16 pb[64 * 72];
  __shared__ float sc[64 * 65];
  __shared__ float rden[64], iwd[64];

  const size_t base = (size_t)b * SEQ;

  for (int i = tid; i < 512; i += 256) {
    int row = i >> 3, part = i & 7;
    *(bf16x8*)&qs[row * 72 + part * 8] =
        *(const bf16x8*)&qbf[(base + qt * 64 + row) * 128 + (h & 1) * 64 + part * 8];
    *(bf16x8*)&ck[row * 72 + part * 8] =
        *(const bf16x8*)&ika[(base + (size_t)row * 64) * DM + h * 64 + part * 8];
  }
  for (int i = tid; i < 4096; i += 256) {
    int c = i & 63, j = i >> 6;
    cxT[j * 72 + c] = ixa[(base + (size_t)c * 64) * DM + h * 64 + j];
  }
  __syncthreads();

  {
    f32x4 d4[4] = {};
#pragma unroll
    for (int kk = 0; kk < 64; kk += 32) {
      bf16x8 a = *(const bf16x8*)&qs[(wd * 16 + (lane & 15)) * 72 + kk + (lane >> 4) * 8];
#pragma unroll
      for (int ni = 0; ni < 4; ++ni) {
        bf16x8 bb = *(const bf16x8*)&ck[(ni * 16 + (lane & 15)) * 72 + kk + (lane >> 4) * 8];
        d4[ni] = __builtin_amdgcn_mfma_f32_16x16x32_bf16(a, bb, d4[ni], 0, 0, 0);
      }
    }
#pragma unroll
    for (int ni = 0; ni < 4; ++ni)
#pragma unroll
      for (int i = 0; i < 4; ++i) {
        int qrow = wd * 16 + (lane >> 4) * 4 + i;
        int c = ni * 16 + (lane & 15);
        sc[qrow * 65 + c] = 0.125f * d4[ni][i];
      }
  }

  float lse = 0.f;
  if (tid < 64) {
    const __bf16* qrow = &qbf[(base + qt * 64 + tid) * 128 + (h & 1) * 64];
    const __bf16* krow = &ika[(base + qt * 64 + tid) * DM + h * 64];
    float dot = 0.f;
#pragma unroll
    for (int p = 0; p < 8; ++p) {
      bf16x8 qa = *(const bf16x8*)&qrow[p * 8];
      bf16x8 ka = *(const bf16x8*)&krow[p * 8];
#pragma unroll
      for (int e = 0; e < 8; ++e) dot += (float)qa[e] * (float)ka[e];
    }
    lse = 0.125f * dot;
  }
  __syncthreads();

  if (tid < 64) {
    int q = tid;
    float m = lse;
    for (int c = 0; c < qt; ++c) m = fmaxf(m, sc[q * 65 + c]);
    float den = 0.f;
    for (int c = 0; c < 64; ++c) {
      float wv = (c < qt) ? __expf(sc[q * 65 + c] - m) : 0.f;
      pb[q * 72 + c] = (__bf16)wv;
      den += wv;
    }
    float iw = __expf(lse - m);
    den += iw;
    rden[q] = 1.f / den;
    iwd[q] = iw;
  }
  __syncthreads();

  {
    f32x4 d4[4] = {};
#pragma unroll
    for (int kk = 0; kk < 64; kk += 32) {
      bf16x8 a = *(const bf16x8*)&pb[(wd * 16 + (lane & 15)) * 72 + kk + (lane >> 4) * 8];
#pragma unroll
      for (int ni = 0; ni < 4; ++ni) {
        bf16x8 bb = *(const bf16x8*)&cxT[(ni * 16 + (lane & 15)) * 72 + kk + (lane >> 4) * 8];
        d4[ni] = __builtin_amdgcn_mfma_f32_16x16x32_bf16(a, bb, d4[ni], 0, 0, 0);
      }
    }
#pragma unroll
    for (int ni = 0; ni < 4; ++ni)
#pragma unroll
      for (int i = 0; i < 4; ++i) {
        int qrow = wd * 16 + (lane >> 4) * 4 + i;
        int j = ni * 16 + (lane & 15);
        size_t srow = base + qt * 64 + qrow;
        float ix = (float)ixa[srow * DM + h * 64 + j];
        float outv = (d4[ni][i] + iwd[qrow] * ix) * rden[qrow];
        float zv = (float)zbf[srow * DM + h * 64 + j];
        y[srow * DM + h * 64 + j] = (__bf16)(outv * zv);
      }
  }
}

// ---------------- launcher
extern "C" void kernel_launch(void* const* d_in, const int* in_sizes, int n_in,
                              void* d_out, int out_size, void* d_ws, size_t ws_size,
                              hipStream_t stream) {
  const float* hidden = (const float*)d_in[0];
  const float* rmsw   = (const float*)d_in[1];
  const float* Win    = (const float*)d_in[2];
  const float* gbias  = (const float*)d_in[3];
  const float* Wout   = (const float*)d_in[4];
  float* out = (float*)d_out;

  char* ws = (char*)d_ws;
  size_t o = 0;
  auto alloc = [&](size_t bytes) { char* p = ws + o; o += (bytes + 255) & ~(size_t)255; return p; };
  __bf16* WinT  = (__bf16*)alloc((size_t)PD * DM * 2);
  __bf16* WoutT = (__bf16*)alloc((size_t)DM * DM * 2);
  __bf16* hy    = (__bf16*)alloc((size_t)TROWS * DM * 2);  // h_bf, reused as y after GEMM1
  __bf16* zbf   = (__bf16*)alloc((size_t)TROWS * DM * 2);
  __bf16* xbf   = (__bf16*)alloc((size_t)TROWS * DM * 2);
  float*  gf    = (float*)alloc((size_t)TROWS * DM * 4);
  __bf16* qbf   = (__bf16*)alloc((size_t)TROWS * 128 * 2);
  __bf16* kbf   = (__bf16*)alloc((size_t)TROWS * 128 * 2);
  __bf16* ixa   = (__bf16*)alloc((size_t)TROWS * DM * 2);
  __bf16* ika   = (__bf16*)alloc((size_t)TROWS * DM * 2);

  tcvt_kernel<<<dim3(PD / 32, DM / 32), dim3(32, 8), 0, stream>>>(Win, WinT, DM, PD);
  tcvt_kernel<<<dim3(DM / 32, DM / 32), dim3(32, 8), 0, stream>>>(Wout, WoutT, DM, DM);
  rmsnorm_kernel<<<TROWS, 256, 0, stream>>>(hidden, rmsw, hy);
  // GEMM1: M=8192, N=3328 -> 64*26 = 1664 blocks (1664 % 8 == 0)
  gemm2p<1><<<dim3((TROWS / 128) * (PD / 128)), 256, 0, stream>>>(
      hy, WinT, PD, DM, gbias, nullptr, nullptr, zbf, xbf, gf, qbf, kbf);
  scan_kernel<<<512, 256, 0, stream>>>(gf, xbf, kbf, ixa, ika);
  attn_kernel<<<dim3(64, 16, 2), 256, 0, stream>>>(qbf, ixa, ika, zbf, hy);
  // GEMM2: M=8192, N=1024 -> 64*8 = 512 blocks (512 % 8 == 0)
  gemm2p<0><<<dim3((TROWS / 128) * (DM / 128)), 256, 0, stream>>>(
      hy, WoutT, DM, DM, nullptr, hidden, out, nullptr, nullptr, nullptr, nullptr, nullptr);
}

// Round 6
// 197.285 us; speedup vs baseline: 1.7266x; 1.0888x over previous
//
#include <hip/hip_runtime.h>
#include <hip/hip_bf16.h>

typedef __bf16 bf16x8 __attribute__((ext_vector_type(8)));
typedef __bf16 bf16x4 __attribute__((ext_vector_type(4)));
typedef float  f32x4  __attribute__((ext_vector_type(4)));

#define DM 1024
#define PD 3328
#define TROWS 8192   // bs*seq = 2*4096
#define SEQ 4096

__device__ __forceinline__ float sigmoidf(float x) { return 1.f / (1.f + __expf(-x)); }

__device__ __forceinline__ void gload16(const void* g, void* l) {
  __builtin_amdgcn_global_load_lds(
      (const __attribute__((address_space(1))) void*)g,
      (__attribute__((address_space(3))) void*)l, 16, 0, 0);
}

// ---------------- transpose + f32->bf16 convert:  in[K][N] f32 -> out[N][K] bf16
__global__ __launch_bounds__(256) void tcvt_kernel(const float* __restrict__ in,
                                                   __bf16* __restrict__ out,
                                                   int K, int N) {
  __shared__ float tile[32][33];
  int n0 = blockIdx.x * 32, k0 = blockIdx.y * 32;
  int tx = threadIdx.x, ty = threadIdx.y;     // 32 x 8
  for (int i = ty; i < 32; i += 8) tile[i][tx] = in[(size_t)(k0 + i) * N + n0 + tx];
  __syncthreads();
  for (int i = ty; i < 32; i += 8) out[(size_t)(n0 + i) * K + k0 + tx] = (__bf16)tile[tx][i];
}

// ---------------- RMSNorm -> bf16
__global__ __launch_bounds__(256) void rmsnorm_kernel(const float* __restrict__ hidden,
                                                      const float* __restrict__ w,
                                                      __bf16* __restrict__ hbf) {
  int r = blockIdx.x;
  int tid = threadIdx.x;
  float4 v = ((const float4*)(hidden + (size_t)r * DM))[tid];
  float ss = v.x * v.x + v.y * v.y + v.z * v.z + v.w * v.w;
#pragma unroll
  for (int off = 32; off > 0; off >>= 1) ss += __shfl_xor(ss, off);
  __shared__ float wsum[4];
  int lane = tid & 63, wid = tid >> 6;
  if (lane == 0) wsum[wid] = ss;
  __syncthreads();
  float tot = wsum[0] + wsum[1] + wsum[2] + wsum[3];
  float inv = rsqrtf(tot * (1.f / 1024.f) + 1e-6f);
  float4 wl = ((const float4*)w)[tid];
  bf16x4 o;
  o[0] = (__bf16)(v.x * inv * wl.x);
  o[1] = (__bf16)(v.y * inv * wl.y);
  o[2] = (__bf16)(v.z * inv * wl.z);
  o[3] = (__bf16)(v.w * inv * wl.w);
  *(bf16x4*)(hbf + (size_t)r * DM + tid * 4) = o;
}

// ---------------- 2-phase MFMA GEMM, 128x128 tile, BK=64, dbuf LDS (64 KiB),
// ONE barrier per K-step — SAME structure as R5, but 512 threads / 8 waves
// (wave tile 32x64) so 2 blocks/CU = 16 resident waves (TLP experiment).
template <int EPI>
__global__ __launch_bounds__(512, 4) void gemm2p(
    const __bf16* __restrict__ A, const __bf16* __restrict__ Bt,
    int N_out, int K,
    const float* __restrict__ gate_bias, const float* __restrict__ shortcut,
    float* __restrict__ outf, __bf16* __restrict__ zbf, __bf16* __restrict__ xbf,
    __bf16* __restrict__ gbf, __bf16* __restrict__ qbf, __bf16* __restrict__ kbf) {
  __shared__ __bf16 As[2][128 * 64];
  __shared__ __bf16 Bs[2][128 * 64];

  const int tid = threadIdx.x;
  const int lane = tid & 63, wid = tid >> 6;   // wid 0..7
  const int wr = wid >> 1, wc = wid & 1;       // 4 x 2 waves, wave tile 32(m) x 64(n)

  // XCD-aware bijective swizzle (grid sizes are multiples of 8)
  const int nwg = gridDim.x;
  const int cpx = nwg >> 3;
  const int swz = (blockIdx.x & 7) * cpx + (blockIdx.x >> 3);
  const int ntx = N_out >> 7;
  const int m0 = (swz / ntx) << 7;
  const int n0 = (swz % ntx) << 7;

  f32x4 acc[2][4] = {};
  const int NT = K >> 6;

  const int arow0 = wr * 32 + (lane & 15);
  const int brow0 = wc * 64 + (lane & 15);

  auto stage = [&](const __bf16* src, int row0, int kt, __bf16* lbuf) {
#pragma unroll
    for (int j = 0; j < 2; ++j) {
      int off16 = tid + j * 512;        // 16B-chunk index; 8 chunks per row
      int row = off16 >> 3, slot = off16 & 7;
      int col = (slot ^ (row & 7)) << 3;  // inverse swizzle on the SOURCE
      gload16(&src[(size_t)(row0 + row) * K + kt + col], lbuf + off16 * 8);
    }
  };
  auto fragrd = [&](const __bf16* buf, int row, int ks) -> bf16x8 {
    int s = ((ks << 2) + (lane >> 4)) ^ (row & 7);   // swizzled read
    return *(const bf16x8*)&buf[(row << 6) + (s << 3)];
  };

  // prologue: tile 0
  stage(A, m0, 0, &As[0][0]);
  stage(Bt, n0, 0, &Bs[0][0]);
  asm volatile("s_waitcnt vmcnt(0)" ::: "memory");
  __builtin_amdgcn_s_barrier();

  for (int t = 0; t < NT; ++t) {
    const __bf16* Ap = &As[t & 1][0];
    const __bf16* Bp = &Bs[t & 1][0];
    // issue next-tile staging first; it stays in flight under this step's
    // ds_reads + MFMAs, then drained by the single vmcnt(0).
    if (t + 1 < NT) {
      stage(A, m0, (t + 1) << 6, &As[(t + 1) & 1][0]);
      stage(Bt, n0, (t + 1) << 6, &Bs[(t + 1) & 1][0]);
    }
#pragma unroll
    for (int ks = 0; ks < 2; ++ks) {
      bf16x8 af[2], bf[4];
#pragma unroll
      for (int m = 0; m < 2; ++m) af[m] = fragrd(Ap, arow0 + m * 16, ks);
#pragma unroll
      for (int n = 0; n < 4; ++n) bf[n] = fragrd(Bp, brow0 + n * 16, ks);
      __builtin_amdgcn_s_setprio(1);
#pragma unroll
      for (int m = 0; m < 2; ++m)
#pragma unroll
        for (int n = 0; n < 4; ++n)
          acc[m][n] = __builtin_amdgcn_mfma_f32_16x16x32_bf16(af[m], bf[n], acc[m][n], 0, 0, 0);
      __builtin_amdgcn_s_setprio(0);
    }
    asm volatile("s_waitcnt vmcnt(0)" ::: "memory");
    __builtin_amdgcn_s_barrier();
  }

  // epilogue: C/D map col=lane&15, row=(lane>>4)*4+i
#pragma unroll
  for (int m = 0; m < 2; ++m) {
#pragma unroll
    for (int n = 0; n < 4; ++n) {
#pragma unroll
      for (int i = 0; i < 4; ++i) {
        int r = m0 + wr * 32 + m * 16 + ((lane >> 4) << 2) + i;
        int c = n0 + wc * 64 + n * 16 + (lane & 15);
        float v = acc[m][n][i];
        if (EPI == 1) {
          if (c < 1024)       zbf[(size_t)r * DM + c] = (__bf16)sigmoidf(v);
          else if (c < 2048)  xbf[(size_t)r * DM + (c - 1024)] = (__bf16)v;
          else if (c < 3072)  gbf[(size_t)r * DM + (c - 2048)] = (__bf16)sigmoidf(v + gate_bias[c - 2048]);
          else if (c < 3200)  qbf[(size_t)r * 128 + (c - 3072)] = (__bf16)v;
          else                kbf[(size_t)r * 128 + (c - 3200)] = (__bf16)v;
        } else {
          outf[(size_t)r * DM + c] = v + shortcut[(size_t)r * DM + c];
        }
      }
    }
  }
}

// ---------------- per-chunk first-order scan (f32 state), thread = one d-channel
__global__ __launch_bounds__(256) void scan_kernel(const __bf16* __restrict__ g,
                                                   const __bf16* __restrict__ x,
                                                   const __bf16* __restrict__ kin,
                                                   __bf16* __restrict__ ixa,
                                                   __bf16* __restrict__ ika) {
  int bx = blockIdx.x;            // 2*64*4 = 512 blocks
  int part = bx & 3;
  int c = (bx >> 2) & 63;
  int b = bx >> 8;
  int d = part * 256 + threadIdx.x;
  size_t base = (size_t)b * SEQ + (size_t)c * 64;
  float sx = 0.f, sk = 0.f;
  for (int t = 0; t < 64; ++t) {
    size_t row = base + t;
    float gg = (float)g[row * DM + d];
    float xv = (float)x[row * DM + d];
    float kv = (float)kin[row * 128 + (d & 127)];
    sx = gg * (sx - xv) + xv;   // = g*prev + (1-g)*x
    sk = gg * (sk - kv) + kv;
    ixa[row * DM + d] = (__bf16)sx;
    ika[row * DM + d] = (__bf16)sk;
  }
}

// ---------------- attention: block = (qtile 64 queries, head, batch); 4 waves
__global__ __launch_bounds__(256) void attn_kernel(const __bf16* __restrict__ qbf,
                                                   const __bf16* __restrict__ ixa,
                                                   const __bf16* __restrict__ ika,
                                                   const __bf16* __restrict__ zbf,
                                                   __bf16* __restrict__ y) {
  const int qt = blockIdx.x;   // 0..63 query chunk
  const int h  = blockIdx.y;   // 0..15
  const int b  = blockIdx.z;   // 0..1
  const int tid = threadIdx.x;
  const int lane = tid & 63, wd = tid >> 6;

  __shared__ __bf16 qs[64 * 72];
  __shared__ __bf16 ck[64 * 72];
  __shared__ __bf16 cxT[64 * 72];
  __shared__ __bf16 pb[64 * 72];
  __shared__ float sc[64 * 65];
  __shared__ float rden[64], iwd[64];

  const size_t base = (size_t)b * SEQ;

  for (int i = tid; i < 512; i += 256) {
    int row = i >> 3, part = i & 7;
    *(bf16x8*)&qs[row * 72 + part * 8] =
        *(const bf16x8*)&qbf[(base + qt * 64 + row) * 128 + (h & 1) * 64 + part * 8];
    *(bf16x8*)&ck[row * 72 + part * 8] =
        *(const bf16x8*)&ika[(base + (size_t)row * 64) * DM + h * 64 + part * 8];
  }
  for (int i = tid; i < 4096; i += 256) {
    int c = i & 63, j = i >> 6;
    cxT[j * 72 + c] = ixa[(base + (size_t)c * 64) * DM + h * 64 + j];
  }
  __syncthreads();

  {
    f32x4 d4[4] = {};
#pragma unroll
    for (int kk = 0; kk < 64; kk += 32) {
      bf16x8 a = *(const bf16x8*)&qs[(wd * 16 + (lane & 15)) * 72 + kk + (lane >> 4) * 8];
#pragma unroll
      for (int ni = 0; ni < 4; ++ni) {
        bf16x8 bb = *(const bf16x8*)&ck[(ni * 16 + (lane & 15)) * 72 + kk + (lane >> 4) * 8];
        d4[ni] = __builtin_amdgcn_mfma_f32_16x16x32_bf16(a, bb, d4[ni], 0, 0, 0);
      }
    }
#pragma unroll
    for (int ni = 0; ni < 4; ++ni)
#pragma unroll
      for (int i = 0; i < 4; ++i) {
        int qrow = wd * 16 + (lane >> 4) * 4 + i;
        int c = ni * 16 + (lane & 15);
        sc[qrow * 65 + c] = 0.125f * d4[ni][i];
      }
  }

  float lse = 0.f;
  if (tid < 64) {
    const __bf16* qrow = &qbf[(base + qt * 64 + tid) * 128 + (h & 1) * 64];
    const __bf16* krow = &ika[(base + qt * 64 + tid) * DM + h * 64];
    float dot = 0.f;
#pragma unroll
    for (int p = 0; p < 8; ++p) {
      bf16x8 qa = *(const bf16x8*)&qrow[p * 8];
      bf16x8 ka = *(const bf16x8*)&krow[p * 8];
#pragma unroll
      for (int e = 0; e < 8; ++e) dot += (float)qa[e] * (float)ka[e];
    }
    lse = 0.125f * dot;
  }
  __syncthreads();

  if (tid < 64) {
    int q = tid;
    float m = lse;
    for (int c = 0; c < qt; ++c) m = fmaxf(m, sc[q * 65 + c]);
    float den = 0.f;
    for (int c = 0; c < 64; ++c) {
      float wv = (c < qt) ? __expf(sc[q * 65 + c] - m) : 0.f;
      pb[q * 72 + c] = (__bf16)wv;
      den += wv;
    }
    float iw = __expf(lse - m);
    den += iw;
    rden[q] = 1.f / den;
    iwd[q] = iw;
  }
  __syncthreads();

  {
    f32x4 d4[4] = {};
#pragma unroll
    for (int kk = 0; kk < 64; kk += 32) {
      bf16x8 a = *(const bf16x8*)&pb[(wd * 16 + (lane & 15)) * 72 + kk + (lane >> 4) * 8];
#pragma unroll
      for (int ni = 0; ni < 4; ++ni) {
        bf16x8 bb = *(const bf16x8*)&cxT[(ni * 16 + (lane & 15)) * 72 + kk + (lane >> 4) * 8];
        d4[ni] = __builtin_amdgcn_mfma_f32_16x16x32_bf16(a, bb, d4[ni], 0, 0, 0);
      }
    }
#pragma unroll
    for (int ni = 0; ni < 4; ++ni)
#pragma unroll
      for (int i = 0; i < 4; ++i) {
        int qrow = wd * 16 + (lane >> 4) * 4 + i;
        int j = ni * 16 + (lane & 15);
        size_t srow = base + qt * 64 + qrow;
        float ix = (float)ixa[srow * DM + h * 64 + j];
        float outv = (d4[ni][i] + iwd[qrow] * ix) * rden[qrow];
        float zv = (float)zbf[srow * DM + h * 64 + j];
        y[srow * DM + h * 64 + j] = (__bf16)(outv * zv);
      }
  }
}

// ---------------- launcher
extern "C" void kernel_launch(void* const* d_in, const int* in_sizes, int n_in,
                              void* d_out, int out_size, void* d_ws, size_t ws_size,
                              hipStream_t stream) {
  const float* hidden = (const float*)d_in[0];
  const float* rmsw   = (const float*)d_in[1];
  const float* Win    = (const float*)d_in[2];
  const float* gbias  = (const float*)d_in[3];
  const float* Wout   = (const float*)d_in[4];
  float* out = (float*)d_out;

  char* ws = (char*)d_ws;
  size_t o = 0;
  auto alloc = [&](size_t bytes) { char* p = ws + o; o += (bytes + 255) & ~(size_t)255; return p; };
  __bf16* WinT  = (__bf16*)alloc((size_t)PD * DM * 2);
  __bf16* WoutT = (__bf16*)alloc((size_t)DM * DM * 2);
  __bf16* hy    = (__bf16*)alloc((size_t)TROWS * DM * 2);  // h_bf, reused as y after GEMM1
  __bf16* zbf   = (__bf16*)alloc((size_t)TROWS * DM * 2);
  __bf16* xbf   = (__bf16*)alloc((size_t)TROWS * DM * 2);
  __bf16* gbf   = (__bf16*)alloc((size_t)TROWS * DM * 2);
  __bf16* qbf   = (__bf16*)alloc((size_t)TROWS * 128 * 2);
  __bf16* kbf   = (__bf16*)alloc((size_t)TROWS * 128 * 2);
  __bf16* ixa   = (__bf16*)alloc((size_t)TROWS * DM * 2);
  __bf16* ika   = (__bf16*)alloc((size_t)TROWS * DM * 2);

  tcvt_kernel<<<dim3(PD / 32, DM / 32), dim3(32, 8), 0, stream>>>(Win, WinT, DM, PD);
  tcvt_kernel<<<dim3(DM / 32, DM / 32), dim3(32, 8), 0, stream>>>(Wout, WoutT, DM, DM);
  rmsnorm_kernel<<<TROWS, 256, 0, stream>>>(hidden, rmsw, hy);
  // GEMM1: M=8192, N=3328 -> 64*26 = 1664 blocks (1664 % 8 == 0)
  gemm2p<1><<<dim3((TROWS / 128) * (PD / 128)), 512, 0, stream>>>(
      hy, WinT, PD, DM, gbias, nullptr, nullptr, zbf, xbf, gbf, qbf, kbf);
  scan_kernel<<<512, 256, 0, stream>>>(gbf, xbf, kbf, ixa, ika);
  attn_kernel<<<dim3(64, 16, 2), 256, 0, stream>>>(qbf, ixa, ika, zbf, hy);
  // GEMM2: M=8192, N=1024 -> 64*8 = 512 blocks (512 % 8 == 0)
  gemm2p<0><<<dim3((TROWS / 128) * (DM / 128)), 512, 0, stream>>>(
      hy, WoutT, DM, DM, nullptr, hidden, out, nullptr, nullptr, nullptr, nullptr, nullptr);
}